// Round 1
// 309.462 us; speedup vs baseline: 1.0648x; 1.0648x over previous
//
#include <hip/hip_runtime.h>
#include <hip/hip_bf16.h>

typedef __attribute__((ext_vector_type(8))) short short8;
typedef __attribute__((ext_vector_type(4))) float floatx4;

#define REG_CAP 106496   // per-shard pair-region capacity (~100K expected + slack)

__device__ __forceinline__ float bf_lo(unsigned int u) { return __uint_as_float(u << 16); }
__device__ __forceinline__ float bf_hi(unsigned int u) { return __uint_as_float(u & 0xffff0000u); }

__device__ __forceinline__ unsigned short f2bf_rne(float f) {
    unsigned u = __float_as_uint(f);
    unsigned rb = (u >> 16) & 1u;
    u += 0x7fffu + rb;
    return (unsigned short)(u >> 16);
}
__device__ __forceinline__ unsigned int pack_bf2(float x, float y) {
    return (unsigned int)f2bf_rne(x) | ((unsigned int)f2bf_rne(y) << 16);
}

// ---------------- prep: fused edge-binning + deg-count (blocks [0,nBin)) + convert/pack (rest) ----------------
// shard_cur[s] holds pure counts (region base = s*REG_CAP), pre-zeroed by memset.
// pair = (u64)dst << 32 | src.  deg[] atomically counted here (was a separate 800K-edge pass).

__global__ __launch_bounds__(256) void prep_kernel(const int* __restrict__ src,
                                                   const int* __restrict__ dst,
                                                   int* __restrict__ shard_cur,
                                                   int* __restrict__ deg,
                                                   unsigned long long* __restrict__ pairs, int E, int nBin,
                                                   const float* __restrict__ x,
                                                   const float* __restrict__ W1,
                                                   const float* __restrict__ W2,
                                                   const float* __restrict__ W3,
                                                   const float* __restrict__ Wp, const float* __restrict__ bp,
                                                   const float* __restrict__ Wc, const float* __restrict__ bc,
                                                   unsigned int* __restrict__ xb,
                                                   unsigned int* __restrict__ W1b,
                                                   unsigned int* __restrict__ W2b,
                                                   unsigned int* __restrict__ W3b,
                                                   unsigned int* __restrict__ Whb,
                                                   float* __restrict__ hbias,
                                                   int nx) {
    if ((int)blockIdx.x < nBin) {
        // ---- bin part ----
        __shared__ int cnt[8];
        __shared__ int base[8];
        const int chunk = (E + nBin - 1) / nBin;
        const int lo = blockIdx.x * chunk;
        const int hi = min(lo + chunk, E);
        if (threadIdx.x < 8) cnt[threadIdx.x] = 0;
        __syncthreads();
        for (int e = lo + threadIdx.x; e < hi; e += 256) {
            int d = dst[e];
            atomicAdd(&cnt[(d >> 8) & 7], 1);
            atomicAdd(&deg[d], 1);          // fused degree count
        }
        __syncthreads();
        if (threadIdx.x < 8) {
            base[threadIdx.x] = atomicAdd(&shard_cur[threadIdx.x], cnt[threadIdx.x]);
            cnt[threadIdx.x] = 0;
        }
        __syncthreads();
        for (int e = lo + threadIdx.x; e < hi; e += 256) {
            int d = dst[e];
            int s = (d >> 8) & 7;
            int pos = s * REG_CAP + base[s] + atomicAdd(&cnt[s], 1);
            if (pos < (s + 1) * REG_CAP)
                pairs[pos] = ((unsigned long long)(unsigned int)d << 32) | (unsigned int)src[e];
        }
        return;
    }
    // ---- convert part ----
    int i = (blockIdx.x - nBin) * 256 + threadIdx.x;
    const int T0 = nx;            // x pairs
    const int T1 = T0 + 4096;     // W1 128x64
    const int T2 = T1 + 8192;     // W2 128x128
    const int T3 = T2 + 4096;     // W3 64x128
    const int T4 = T3 + 2560;     // Whb 80x64
    const int T5 = T4 + 80;       // hbias
    if (i < T0) {
        float2 f = ((const float2*)x)[i];
        xb[i] = pack_bf2(f.x, f.y);
    } else if (i < T1) {
        float2 f = ((const float2*)W1)[i - T0];
        W1b[i - T0] = pack_bf2(f.x, f.y);
    } else if (i < T2) {
        float2 f = ((const float2*)W2)[i - T1];
        W2b[i - T1] = pack_bf2(f.x, f.y);
    } else if (i < T3) {
        float2 f = ((const float2*)W3)[i - T2];
        W3b[i - T2] = pack_bf2(f.x, f.y);
    } else if (i < T4) {
        int j = i - T3;
        int r = j >> 5, c = (j & 31) * 2;
        float v0 = 0.f, v1 = 0.f;
        if (r < 64)      { v0 = Wp[r * 64 + c]; v1 = Wp[r * 64 + c + 1]; }
        else if (r < 74) { v0 = Wc[(r - 64) * 64 + c]; v1 = Wc[(r - 64) * 64 + c + 1]; }
        Whb[j] = pack_bf2(v0, v1);
    } else if (i < T5) {
        int j = i - T4;
        float v = 0.f;
        if (j < 64)      v = bp[j];
        else if (j < 74) v = bc[j - 64];
        hbias[j] = v;
    }
}

__global__ __launch_bounds__(256) void scatter_binned_kernel(const unsigned long long* __restrict__ pairs,
                                                             const int* __restrict__ shard_cur,
                                                             int* __restrict__ cursor,
                                                             unsigned short* __restrict__ csr_src, int nSub) {
    const int s   = blockIdx.x & 7;
    const int sub = blockIdx.x >> 3;
    const int cnt = shard_cur[s];
    const int per = (cnt + nSub - 1) / nSub;
    const int lo = s * REG_CAP + sub * per;
    const int hi = min(lo + per, s * REG_CAP + cnt);
    for (int i = lo + threadIdx.x; i < hi; i += 256) {
        unsigned long long pr = pairs[i];
        int pos = atomicAdd(&cursor[(int)(pr >> 32)], 1);
        csr_src[pos] = (unsigned short)(pr & 0xffffu);
    }
}

// ---------------- scan: per-block partial sums, then local scan w/ inline partial prefix ----------------

__global__ __launch_bounds__(256) void partial_sum_kernel(const int* __restrict__ deg,
                                                          int* __restrict__ partial, int n) {
    __shared__ int s[256];
    int t = threadIdx.x;
    int i = blockIdx.x * 256 + t;
    s[t] = (i < n) ? deg[i] : 0;
    __syncthreads();
    for (int off = 128; off > 0; off >>= 1) {
        if (t < off) s[t] += s[t + off];
        __syncthreads();
    }
    if (t == 0) partial[blockIdx.x] = s[0];
}

__global__ __launch_bounds__(256) void local_scan_kernel(const int* __restrict__ deg,
                                                         const int* __restrict__ partial,
                                                         int* __restrict__ offsets,
                                                         int* __restrict__ cursor, int nblocks, int n) {
    __shared__ int sp[256];
    __shared__ int s[256];
    int t = threadIdx.x;
    sp[t] = (t < nblocks) ? partial[t] : 0;
    __syncthreads();
    for (int off = 1; off < 256; off <<= 1) {
        int u = (t >= off) ? sp[t - off] : 0;
        __syncthreads();
        sp[t] += u;
        __syncthreads();
    }
    const int blockbase = (blockIdx.x == 0) ? 0 : sp[blockIdx.x - 1];
    if (blockIdx.x == 0 && t == 0) offsets[n] = sp[nblocks - 1];

    int i = blockIdx.x * 256 + t;
    int v = (i < n) ? deg[i] : 0;
    s[t] = v;
    __syncthreads();
    for (int off = 1; off < 256; off <<= 1) {
        int u = (t >= off) ? s[t - off] : 0;
        __syncthreads();
        s[t] += u;
        __syncthreads();
    }
    if (i < n) {
        int o = blockbase + s[t] - v;
        offsets[i] = o;
        cursor[i]  = o;
    }
}

// ---------------- Fused agg + MFMA GEMM per layer ----------------
// Block = 512 threads (8 waves), 32 nodes. Phase A: each wave aggregates 4 nodes
// (identical math to the old dedicated agg kernels) into an LDS tile (bf16, padded
// stride). Phase B: 8 waves MFMA the 32xF_OUT output tile straight from LDS.
// Eliminates the Hb global round-trip entirely; numerics are bit-identical.
// MODE 0: bf16 out + relu.  MODE 3: relu, fp32 emb out, heads MFMA via LDS Ytile.

template <int F_IN, int F_OUT, int MODE>
__global__ __launch_bounds__(512) void fused_agg_gemm_kernel(
        const unsigned long long* __restrict__ xt,      // gather table, F_IN/4 u64 per row
        const int* __restrict__ offsets,
        const unsigned short* __restrict__ csr_src,
        const unsigned short* __restrict__ Wb,          // F_OUT x F_IN bf16
        const float* __restrict__ bias,
        unsigned short* __restrict__ Yb,                // MODE 0 out
        float* __restrict__ Yf,                         // MODE 3: emb out (fp32)
        float* __restrict__ nev, float* __restrict__ cls,
        const unsigned short* __restrict__ Whb, const float* __restrict__ hbias,
        int n) {
    constexpr int KC   = F_IN / 32;     // short8 chunks per row
    constexpr int XSTR = F_IN / 4;      // u64 per gather-table row
    constexpr int HSTR = F_IN + 8;      // LDS row stride (shorts), breaks pow2 banks
    __shared__ __align__(16) unsigned short Ht[32 * HSTR];
    __shared__ __align__(16) unsigned short Yt[(MODE == 3) ? 32 * 72 : 16];

    const int lane = threadIdx.x & 63;
    const int wv   = threadIdx.x >> 6;      // 0..7
    const int m0   = blockIdx.x * 32;

    // ---------- Phase A: aggregation, 4 nodes per wave ----------
    if (F_IN == 64) {
        const int quad = lane >> 4;
        const int c    = lane & 15;
#pragma unroll 1
        for (int i = 0; i < 4; ++i) {
            const int row  = wv * 4 + i;
            const int node = m0 + row;
            if (node < n) {
                const int start = offsets[node];
                const int end   = offsets[node + 1];
                float s0 = 0.f, s1 = 0.f, s2 = 0.f, s3 = 0.f;
                int e = start;
                while (e < end) {
                    int cnt = min(64, end - e);
                    int ii = e + lane; if (ii >= end) ii = end - 1;
                    int idx = csr_src[ii];
                    int j = 0;
                    for (; j + 32 <= cnt; j += 32) {
                        unsigned long long v[8];
#pragma unroll
                        for (int q = 0; q < 8; ++q) {
                            int nb = __shfl(idx, j + q * 4 + quad, 64);
                            v[q] = xt[(size_t)nb * XSTR + c];
                        }
#pragma unroll
                        for (int q = 0; q < 8; ++q) {
                            unsigned int ua = (unsigned int)v[q], ub = (unsigned int)(v[q] >> 32);
                            s0 += bf_lo(ua); s1 += bf_hi(ua); s2 += bf_lo(ub); s3 += bf_hi(ub);
                        }
                    }
                    for (; j + 4 <= cnt; j += 4) {
                        int nb = __shfl(idx, j + quad, 64);
                        unsigned long long v = xt[(size_t)nb * XSTR + c];
                        unsigned int ua = (unsigned int)v, ub = (unsigned int)(v >> 32);
                        s0 += bf_lo(ua); s1 += bf_hi(ua); s2 += bf_lo(ub); s3 += bf_hi(ub);
                    }
                    int rem = cnt - j;
                    if (rem > 0) {                         // wave-uniform
                        int sl = j + quad;
                        sl = (sl < cnt) ? sl : (cnt - 1);  // keep source lane active
                        int nb = __shfl(idx, sl, 64);
                        if (quad < rem) {
                            unsigned long long v = xt[(size_t)nb * XSTR + c];
                            unsigned int ua = (unsigned int)v, ub = (unsigned int)(v >> 32);
                            s0 += bf_lo(ua); s1 += bf_hi(ua); s2 += bf_lo(ub); s3 += bf_hi(ub);
                        }
                    }
                    e += cnt;
                }
                s0 += __shfl(s0, lane ^ 16, 64); s1 += __shfl(s1, lane ^ 16, 64);
                s2 += __shfl(s2, lane ^ 16, 64); s3 += __shfl(s3, lane ^ 16, 64);
                s0 += __shfl(s0, lane ^ 32, 64); s1 += __shfl(s1, lane ^ 32, 64);
                s2 += __shfl(s2, lane ^ 32, 64); s3 += __shfl(s3, lane ^ 32, 64);
                if (quad == 0) {
                    float inv = 1.0f / fmaxf((float)(end - start), 1.0f);
                    unsigned long long sv = xt[(size_t)node * XSTR + c];
                    unsigned int ua = (unsigned int)sv, ub = (unsigned int)(sv >> 32);
                    unsigned int o0 = pack_bf2(s0 * inv + bf_lo(ua), s1 * inv + bf_hi(ua));
                    unsigned int o1 = pack_bf2(s2 * inv + bf_lo(ub), s3 * inv + bf_hi(ub));
                    *(unsigned long long*)&Ht[row * HSTR + c * 4] =
                        ((unsigned long long)o1 << 32) | o0;
                }
            } else if (quad == 0) {
                *(unsigned long long*)&Ht[row * HSTR + c * 4] = 0ull;
            }
        }
    } else {
        const int half = lane >> 5;
        const int c    = lane & 31;
#pragma unroll 1
        for (int i = 0; i < 4; ++i) {
            const int row  = wv * 4 + i;
            const int node = m0 + row;
            if (node < n) {
                const int start = offsets[node];
                const int end   = offsets[node + 1];
                float s0 = 0.f, s1 = 0.f, s2 = 0.f, s3 = 0.f;
                int e = start;
                while (e < end) {
                    int cnt = min(64, end - e);
                    int ii = e + lane; if (ii >= end) ii = end - 1;
                    int idx = csr_src[ii];
                    int j = 0;
                    for (; j + 16 <= cnt; j += 16) {
                        unsigned long long v[8];
#pragma unroll
                        for (int q = 0; q < 8; ++q) {
                            int nb = __shfl(idx, j + q * 2 + half, 64);
                            v[q] = xt[(size_t)nb * XSTR + c];
                        }
#pragma unroll
                        for (int q = 0; q < 8; ++q) {
                            unsigned int ua = (unsigned int)v[q], ub = (unsigned int)(v[q] >> 32);
                            s0 += bf_lo(ua); s1 += bf_hi(ua); s2 += bf_lo(ub); s3 += bf_hi(ub);
                        }
                    }
                    for (; j + 2 <= cnt; j += 2) {
                        int nb = __shfl(idx, j + half, 64);
                        unsigned long long v = xt[(size_t)nb * XSTR + c];
                        unsigned int ua = (unsigned int)v, ub = (unsigned int)(v >> 32);
                        s0 += bf_lo(ua); s1 += bf_hi(ua); s2 += bf_lo(ub); s3 += bf_hi(ub);
                    }
                    if (j < cnt) {                         // wave-uniform, rem == 1
                        int nb = __shfl(idx, j, 64);
                        if (half == 0) {
                            unsigned long long v = xt[(size_t)nb * XSTR + c];
                            unsigned int ua = (unsigned int)v, ub = (unsigned int)(v >> 32);
                            s0 += bf_lo(ua); s1 += bf_hi(ua); s2 += bf_lo(ub); s3 += bf_hi(ub);
                        }
                    }
                    e += cnt;
                }
                s0 += __shfl(s0, lane ^ 32, 64); s1 += __shfl(s1, lane ^ 32, 64);
                s2 += __shfl(s2, lane ^ 32, 64); s3 += __shfl(s3, lane ^ 32, 64);
                if (half == 0) {
                    float inv = 1.0f / fmaxf((float)(end - start), 1.0f);
                    unsigned long long sv = xt[(size_t)node * XSTR + c];
                    unsigned int ua = (unsigned int)sv, ub = (unsigned int)(sv >> 32);
                    unsigned int o0 = pack_bf2(s0 * inv + bf_lo(ua), s1 * inv + bf_hi(ua));
                    unsigned int o1 = pack_bf2(s2 * inv + bf_lo(ub), s3 * inv + bf_hi(ub));
                    *(unsigned long long*)&Ht[row * HSTR + c * 4] =
                        ((unsigned long long)o1 << 32) | o0;
                }
            } else if (half == 0) {
                *(unsigned long long*)&Ht[row * HSTR + c * 4] = 0ull;
            }
        }
    }
    __syncthreads();

    // ---------- Phase B: MFMA on the 32-row tile ----------
    const int quad = lane >> 4;
    const int r16  = lane & 15;

    if (MODE == 0) {
        // 32 x F_OUT(=128): 2 row-groups x 8 col-groups = 16 tiles, 2 per wave
        const int rowg = wv & 1;
        const int cg0  = (wv >> 1) * 2;
        short8 a[KC];
#pragma unroll
        for (int c = 0; c < KC; ++c)
            a[c] = *(const short8*)&Ht[(16 * rowg + r16) * HSTR + 32 * c + quad * 8];

        floatx4 acc[2];
#pragma unroll
        for (int j = 0; j < 2; ++j)
#pragma unroll
            for (int r = 0; r < 4; ++r) acc[j][r] = 0.f;

#pragma unroll
        for (int j = 0; j < 2; ++j)
#pragma unroll
            for (int c = 0; c < KC; ++c) {
                short8 b = *(const short8*)&Wb[(size_t)(16 * (cg0 + j) + r16) * F_IN + 32 * c + quad * 8];
                acc[j] = __builtin_amdgcn_mfma_f32_16x16x32_bf16(a[c], b, acc[j], 0, 0, 0);
            }

#pragma unroll
        for (int r = 0; r < 4; ++r) {
            const int mm = m0 + 16 * rowg + quad * 4 + r;
            if (mm >= n) continue;
#pragma unroll
            for (int j = 0; j < 2; ++j) {
                const int o = 16 * (cg0 + j) + r16;
                Yb[(size_t)mm * F_OUT + o] = f2bf_rne(fmaxf(acc[j][r] + bias[o], 0.f));
            }
        }
    } else {
        // layer3: 32 x 64 = 2 x 4 tiles, 1 per wave; then heads from LDS Ytile
        const int rowg = wv & 1;
        const int cg   = wv >> 1;      // 0..3
        short8 a[KC];
#pragma unroll
        for (int c = 0; c < KC; ++c)
            a[c] = *(const short8*)&Ht[(16 * rowg + r16) * HSTR + 32 * c + quad * 8];

        floatx4 acc;
#pragma unroll
        for (int r = 0; r < 4; ++r) acc[r] = 0.f;

#pragma unroll
        for (int c = 0; c < KC; ++c) {
            short8 b = *(const short8*)&Wb[(size_t)(16 * cg + r16) * F_IN + 32 * c + quad * 8];
            acc = __builtin_amdgcn_mfma_f32_16x16x32_bf16(a[c], b, acc, 0, 0, 0);
        }

#pragma unroll
        for (int r = 0; r < 4; ++r) {
            const int lr = 16 * rowg + quad * 4 + r;
            const int mm = m0 + lr;
            const int o  = 16 * cg + r16;
            if (mm < n) {
                float v = fmaxf(acc[r] + bias[o], 0.f);
                Yf[(size_t)mm * 64 + o] = v;
                Yt[lr * 72 + o] = f2bf_rne(v);
            } else {
                Yt[lr * 72 + o] = 0;
            }
        }
        __syncthreads();

        // heads: 32 x 80 = 2 x 5 tiles = 10, waves 0..7 take t=wv, waves 0..1 also t=8+wv
        for (int t = wv; t < 10; t += 8) {
            const int rg  = t & 1;
            const int cg2 = t >> 1;    // 0..4
            short8 a2[2];
#pragma unroll
            for (int c = 0; c < 2; ++c)
                a2[c] = *(const short8*)&Yt[(16 * rg + r16) * 72 + 32 * c + quad * 8];

            floatx4 acc2;
#pragma unroll
            for (int r = 0; r < 4; ++r) acc2[r] = 0.f;

#pragma unroll
            for (int c = 0; c < 2; ++c) {
                short8 b = *(const short8*)&Whb[(size_t)(16 * cg2 + r16) * 64 + 32 * c + quad * 8];
                acc2 = __builtin_amdgcn_mfma_f32_16x16x32_bf16(a2[c], b, acc2, 0, 0, 0);
            }

#pragma unroll
            for (int r = 0; r < 4; ++r) {
                const int mm = m0 + 16 * rg + quad * 4 + r;
                if (mm >= n) continue;
                const int o = 16 * cg2 + r16;
                float v = acc2[r] + hbias[o];
                if (o < 64)      nev[(size_t)mm * 64 + o] = v;
                else if (o < 74) cls[(size_t)mm * 10 + (o - 64)] = v;
            }
        }
    }
}

// ---------------- launch ----------------

extern "C" void kernel_launch(void* const* d_in, const int* in_sizes, int n_in,
                              void* d_out, int out_size, void* d_ws, size_t ws_size,
                              hipStream_t stream) {
    const float* x  = (const float*)d_in[0];
    const int*   ei = (const int*)d_in[1];
    const float* W1 = (const float*)d_in[2];
    const float* b1 = (const float*)d_in[3];
    const float* W2 = (const float*)d_in[4];
    const float* b2 = (const float*)d_in[5];
    const float* W3 = (const float*)d_in[6];
    const float* b3 = (const float*)d_in[7];
    const float* Wp = (const float*)d_in[8];
    const float* bp = (const float*)d_in[9];
    const float* Wc = (const float*)d_in[10];
    const float* bc = (const float*)d_in[11];

    const int n = in_sizes[0] / 64;   // 50000
    const int E = in_sizes[1] / 2;    // 800000
    const int* src = ei;
    const int* dst = ei + E;

    const int nScanBlocks = (n + 255) / 256;   // 196

    // workspace layout (deg and shard_cur adjacent: one memset zeroes both)
    int* deg       = (int*)d_ws;              // n
    int* shard_cur = deg + n;                 // 8
    int* offsets   = shard_cur + 8;           // n+1
    int* cursor    = offsets + (n + 1);       // n
    int* partial   = cursor + n;              // 256
    unsigned short* csr_src = (unsigned short*)(partial + 256);   // E u16
    uintptr_t p = (uintptr_t)(csr_src + E);
    p = (p + 255) & ~(uintptr_t)255;
    unsigned long long* pairs = (unsigned long long*)p;        // 8*REG_CAP
    unsigned int* Hb  = (unsigned int*)(pairs + 8 * REG_CAP);  // n*64 (n x 128 bf16)
    unsigned int* Yb  = Hb + (size_t)n * 64;       // n*64 (n x 128 bf16)
    unsigned int* xb  = Yb + (size_t)n * 64;       // n*32 (n x 64 bf16)
    unsigned int* W1b = xb + (size_t)n * 32;       // 4096 uints
    unsigned int* W2b = W1b + 4096;                // 8192
    unsigned int* W3b = W2b + 8192;                // 4096
    unsigned int* Whb = W3b + 4096;                // 2560
    float* hbias = (float*)(Whb + 2560);           // 80

    float* out_emb = (float*)d_out;
    float* out_nev = out_emb + (size_t)n * 64;
    float* out_cls = out_nev + (size_t)n * 64;

    hipMemsetAsync(deg, 0, (size_t)(n + 8) * sizeof(int), stream);

    const int nBin = 256;
    const int convTotal = n * 32 + 4096 + 8192 + 4096 + 2560 + 80;
    const int convBlocks = (convTotal + 255) / 256;
    prep_kernel<<<nBin + convBlocks, 256, 0, stream>>>(
        src, dst, shard_cur, deg, pairs, E, nBin,
        x, W1, W2, W3, Wp, bp, Wc, bc, xb, W1b, W2b, W3b, Whb, hbias, n * 32);

    partial_sum_kernel<<<nScanBlocks, 256, 0, stream>>>(deg, partial, n);
    local_scan_kernel<<<nScanBlocks, 256, 0, stream>>>(deg, partial, offsets, cursor, nScanBlocks, n);

    const int nSub = 64;   // 8 shards x 64 = 512 blocks
    scatter_binned_kernel<<<8 * nSub, 256, 0, stream>>>(pairs, shard_cur, cursor, csr_src, nSub);

    const int gF = (n + 31) / 32;    // 1563 blocks, 512 threads

    // layer 1: agg(x, F=64) + GEMM 64->128 -> Hb (bf16)
    fused_agg_gemm_kernel<64, 128, 0><<<gF, 512, 0, stream>>>(
        (const unsigned long long*)xb, offsets, csr_src,
        (const unsigned short*)W1b, b1, (unsigned short*)Hb,
        nullptr, nullptr, nullptr, nullptr, nullptr, n);

    // layer 2: agg(Hb, F=128) + GEMM 128->128 -> Yb (bf16)
    fused_agg_gemm_kernel<128, 128, 0><<<gF, 512, 0, stream>>>(
        (const unsigned long long*)Hb, offsets, csr_src,
        (const unsigned short*)W2b, b2, (unsigned short*)Yb,
        nullptr, nullptr, nullptr, nullptr, nullptr, n);

    // layer 3: agg(Yb, F=128) + GEMM 128->64 + heads -> out_emb / nev / cls
    fused_agg_gemm_kernel<128, 64, 3><<<gF, 512, 0, stream>>>(
        (const unsigned long long*)Yb, offsets, csr_src,
        (const unsigned short*)W3b, b3, nullptr,
        out_emb, out_nev, out_cls, (const unsigned short*)Whb, hbias, n);
}